// Round 8
// baseline (414.609 us; speedup 1.0000x reference)
//
#include <hip/hip_runtime.h>
#include <hip/hip_cooperative_groups.h>
namespace cg = cooperative_groups;

#define N_NODES 50000
#define N_EDGES 800000
#define IN_DIM 128
#define EMB_DIM 64
#define HID 128
#define OUT_DIM 64
#define NUM_GRAPHS 128
#define E_TOT (N_EDGES + N_NODES)
#define K1 (IN_DIM + EMB_DIM)   // 192
#define NB 391                   // ceil(N_NODES/128) buckets of 128 dst nodes
#define EPB 4096
#define NCHUNK ((N_EDGES + EPB - 1) / EPB)  // 196
#define EPT 16                   // EPB / 256
#define NGRP 12500               // node groups of 4
#define NRG 782                  // row groups of 64 (mgemm)

typedef __attribute__((ext_vector_type(8))) short bf16x8;
typedef __attribute__((ext_vector_type(4))) float f32x4;

__device__ __forceinline__ float gelu_f(float x) {
    float x3 = x * x * x;
    return 0.5f * x * (1.0f + tanhf(0.7978845608028654f * (x + 0.044715f * x3)));
}
__device__ __forceinline__ float lrelu02(float x) { return x > 0.f ? x : 0.2f * x; }
__device__ __forceinline__ float rl_f(float v, int j) {
    return __int_as_float(__builtin_amdgcn_readlane(__float_as_int(v), j));
}
__device__ __forceinline__ unsigned short f2bf(float f) {  // RNE
    unsigned u = __float_as_uint(f);
    unsigned r = (u + 0x7fffu + ((u >> 16) & 1u)) >> 16;
    return (unsigned short)r;
}
__device__ __forceinline__ unsigned pk2bf(float a, float b) {
    return (unsigned)f2bf(a) | ((unsigned)f2bf(b) << 16);
}

struct MegaArgs {
    const float* x; const int* nidx; const int* src; const int* dst; const int* batch;
    const float* emb;
    const float* W1; const float* a1s; const float* a1d; const float* b1;
    const float* W2; const float* a2s; const float* a2d; const float* b2;
    const float* W3; const float* a3s; const float* a3d; const float* b3;
    const float* fcW; const float* fcb;
    float* out;
    unsigned* Abu; float* h3f;                       // aliased region
    unsigned short* hLin; unsigned short* hAct;
    float* asn; float* adn;
    int* rowptr; int* bcnt; int* boff; int* bfill;
    unsigned* barr; int* csr;
    unsigned short* Wt1; unsigned short* Wt2; unsigned short* Wt3;
};

// ================= phase device functions (all grid-stride, any grid>=1 correct) ==============

__device__ void phase_p0(const MegaArgs& A) {
    const int tid = threadIdx.x, bid = blockIdx.x;
    const int lane = tid & 63, wv = tid >> 6;
    const int gtid = bid * 256 + tid;
    const int nthr = gridDim.x * 256;
    for (int i = gtid; i < NB; i += nthr) { A.bcnt[i] = 0; A.bfill[i] = 0; }
    for (int id = gtid; id < 128 * K1; id += nthr) {
        int c = id / K1, k = id - c * K1;
        A.Wt1[c * K1 + k] = f2bf(A.W1[(size_t)k * HID + c]);
    }
    for (int id = gtid; id < 128 * 128; id += nthr) {
        int c = id >> 7, k = id & 127;
        A.Wt2[c * HID + k] = f2bf(A.W2[(size_t)k * HID + c]);
        A.Wt3[c * HID + k] = f2bf(A.W3[(size_t)k * HID + c]);
    }
    for (int g4 = bid; g4 < NGRP; g4 += gridDim.x) {
        int node = g4 * 4 + wv;
        if (node >= N_NODES) continue;
        float2 v = ((const float2*)(A.x + (size_t)node * IN_DIM))[lane];
        float ss = v.x * v.x + v.y * v.y;
#pragma unroll
        for (int o = 32; o; o >>= 1) ss += __shfl_xor(ss, o);
        float nrm = sqrtf(ss);
        if (nrm == 0.f) nrm = 1e-8f;
        float inv = 1.f / nrm;
        unsigned* row = A.Abu + (size_t)node * (K1 / 2);
        row[lane] = pk2bf(v.x * inv, v.y * inv);
        int nid = __builtin_amdgcn_readfirstlane(A.nidx[node]);
        if (lane < 32) {
            float2 e = ((const float2*)(A.emb + (size_t)nid * EMB_DIM))[lane];
            row[64 + lane] = pk2bf(e.x, e.y);
        }
    }
}

__device__ void phase_bhist(const MegaArgs& A, int* h) {
    const int tid = threadIdx.x;
    for (int c = blockIdx.x; c < NCHUNK; c += gridDim.x) {
        for (int i = tid; i < NB; i += 256) h[i] = 0;
        __syncthreads();
        int e0 = c * EPB, e1 = min(e0 + EPB, N_EDGES);
        for (int e = e0 + tid; e < e1; e += 256) atomicAdd(&h[A.dst[e] >> 7], 1);
        __syncthreads();
        for (int i = tid; i < NB; i += 256)
            if (h[i]) atomicAdd(&A.bcnt[i], h[i]);
        __syncthreads();
    }
}

__device__ void phase_bscan(const MegaArgs& A) {
    const int tid = threadIdx.x;
    const int lane = tid & 63;
    if (blockIdx.x == 0 && (tid >> 6) == 0) {
        int run = 0;
        for (int c = 0; c < 7; c++) {
            int i = c * 64 + lane;
            int v = (i < NB) ? A.bcnt[i] : 0;
            int s = v;
#pragma unroll
            for (int o = 1; o < 64; o <<= 1) {
                int u = __shfl_up(s, o);
                if (lane >= o) s += u;
            }
            if (i < NB) A.boff[i] = run + s - v;
            run += __shfl(s, 63);
        }
        if (lane == 0) { A.boff[NB] = N_EDGES; A.rowptr[N_NODES] = E_TOT; }
    }
}

__device__ void phase_passA(const MegaArgs& A, int* h, int* base) {
    const int tid = threadIdx.x;
    for (int c = blockIdx.x; c < NCHUNK; c += gridDim.x) {
        for (int i = tid; i < NB; i += 256) h[i] = 0;
        __syncthreads();
        int e0 = c * EPB;
        int tag[EPT];
#pragma unroll
        for (int i = 0; i < EPT; i++) {
            int e = e0 + i * 256 + tid;
            tag[i] = -1;
            if (e < N_EDGES) {
                int b = A.dst[e] >> 7;
                int r = atomicAdd(&h[b], 1);
                tag[i] = (b << 12) | r;
            }
        }
        __syncthreads();
        for (int i = tid; i < NB; i += 256)
            base[i] = h[i] ? atomicAdd(&A.bfill[i], h[i]) : 0;
        __syncthreads();
#pragma unroll
        for (int i = 0; i < EPT; i++) {
            if (tag[i] >= 0) {
                int e = e0 + i * 256 + tid;
                int b = tag[i] >> 12, r = tag[i] & 0xfff;
                A.barr[A.boff[b] + base[b] + r] =
                    (unsigned)A.src[e] | ((unsigned)(A.dst[e] & 127) << 16);
            }
        }
        __syncthreads();
    }
}

__device__ void phase_passB(const MegaArgs& A, int* dcnt, int* dsum, int* locOff) {
    const int tid = threadIdx.x;
    for (int b = blockIdx.x; b < NB; b += gridDim.x) {
        int n0 = b << 7;
        int cnt = min(128, N_NODES - n0);
        int eb = A.boff[b], ee = A.boff[b + 1];
        if (tid < 128) dcnt[tid] = 0;
        __syncthreads();
        for (int i = eb + tid; i < ee; i += 256) atomicAdd(&dcnt[A.barr[i] >> 16], 1);
        __syncthreads();
        int v = 0;
        if (tid < 128) {
            v = (tid < cnt) ? dcnt[tid] + 1 : 0;
            dsum[tid] = v;
        }
        __syncthreads();
        for (int o = 1; o < 128; o <<= 1) {
            int u = (tid >= o && tid < 128) ? dsum[tid - o] : 0;
            __syncthreads();
            if (tid < 128) dsum[tid] += u;
            __syncthreads();
        }
        int csrBase = eb + n0;
        if (tid < 128) {
            locOff[tid] = dsum[tid] - v;
            dcnt[tid] = 0;
        }
        if (tid < cnt) {
            int loc = dsum[tid] - v;
            A.rowptr[n0 + tid] = csrBase + loc;
            A.csr[csrBase + loc] = n0 + tid;  // self loop at slot 0
        }
        __syncthreads();
        for (int i = eb + tid; i < ee; i += 256) {
            unsigned vv = A.barr[i];
            int dl = vv >> 16;
            int s = (int)(vv & 0xffffu);
            int k = atomicAdd(&dcnt[dl], 1);
            A.csr[csrBase + locOff[dl] + 1 + k] = s;
        }
        __syncthreads();
    }
}

template <int K>
__device__ void phase_mgemm(const unsigned short* __restrict__ Abf, const unsigned short* __restrict__ Wt,
                            const float* __restrict__ a_s, const float* __restrict__ a_d,
                            unsigned short* __restrict__ Hbf, float* __restrict__ asn,
                            float* __restrict__ adn) {
    const int lane = threadIdx.x & 63;
    const int wv = threadIdx.x >> 6;
    const int l15 = lane & 15, quad = lane >> 4;
    constexpr int NK = K / 32;
    for (int rg = blockIdx.x; rg < NRG; rg += gridDim.x) {
        int rowbase = rg * 64 + wv * 16;
        if (rowbase >= N_NODES) continue;
        const unsigned short* Abase = Abf + (size_t)(rowbase + l15) * K + quad * 8;
        bf16x8 afr[NK];
#pragma unroll
        for (int i = 0; i < NK; i++) afr[i] = *(const bf16x8*)(Abase + i * 32);
        f32x4 acc[8];
#pragma unroll
        for (int t = 0; t < 8; t++) acc[t] = (f32x4){0.f, 0.f, 0.f, 0.f};
#pragma unroll
        for (int i = 0; i < NK; i++) {
#pragma unroll
            for (int t = 0; t < 8; t++) {
                bf16x8 bf = *(const bf16x8*)(Wt + (size_t)(t * 16 + l15) * K + i * 32 + quad * 8);
                acc[t] = __builtin_amdgcn_mfma_f32_16x16x32_bf16(afr[i], bf, acc[t], 0, 0, 0);
            }
        }
        float asc[8], adc[8];
#pragma unroll
        for (int t = 0; t < 8; t++) { asc[t] = a_s[t * 16 + l15]; adc[t] = a_d[t * 16 + l15]; }
#pragma unroll
        for (int r = 0; r < 4; r++) {
            int row = rowbase + quad * 4 + r;
            float ps = 0.f, pd = 0.f;
#pragma unroll
            for (int t = 0; t < 8; t++) {
                float v = acc[t][r];
                Hbf[(size_t)row * HID + t * 16 + l15] = f2bf(v);
                ps = fmaf(v, asc[t], ps);
                pd = fmaf(v, adc[t], pd);
            }
#pragma unroll
            for (int o = 1; o < 16; o <<= 1) {
                ps += __shfl_xor(ps, o);
                pd += __shfl_xor(pd, o);
            }
            if (l15 == 0) { asn[row] = ps; adn[row] = pd; }
        }
    }
}

template <bool OUT32>
__device__ void phase_aggr(const MegaArgs& A, const unsigned short* __restrict__ hbf,
                           const float* __restrict__ bias, void* __restrict__ outp, char* smem) {
    float* sh_e = (float*)smem;       // [4][64]
    int* sh_s = (int*)(smem + 1024);  // [4][64]
    const int lane = threadIdx.x & 63;
    const int w = threadIdx.x >> 6;
    const unsigned* hu = (const unsigned*)hbf;
    const int* rowptr = A.rowptr;
    const int* csr = A.csr;
    const float* asn = A.asn;
    const float* adn = A.adn;
    for (int ng = blockIdx.x; ng < NGRP; ng += gridDim.x) {
        int node = ng * 4 + w;
        if (node >= N_NODES) continue;
        int st = rowptr[node], en = rowptr[node + 1];
        int deg = en - st;
        float ad = adn[node];
        float2 acc = make_float2(0.f, 0.f);
        if (deg <= 64) {
            int s = 0;
            float l = -1e30f;
            if (lane < deg) {
                s = csr[st + lane];
                l = lrelu02(asn[s] + ad);
            }
            float m = l;
#pragma unroll
            for (int o = 32; o; o >>= 1) m = fmaxf(m, __shfl_xor(m, o));
            float e = (lane < deg) ? __expf(l - m) : 0.f;
            float ssum = e;
#pragma unroll
            for (int o = 32; o; o >>= 1) ssum += __shfl_xor(ssum, o);
            float coef = e / ssum;
            int j = 0;
            for (; j + 8 <= deg; j += 8) {
                int si[8]; float ci[8]; unsigned vi[8];
#pragma unroll
                for (int q = 0; q < 8; q++) {
                    si[q] = __builtin_amdgcn_readlane(s, j + q);
                    ci[q] = rl_f(coef, j + q);
                }
#pragma unroll
                for (int q = 0; q < 8; q++) vi[q] = hu[(size_t)si[q] * 64 + lane];
#pragma unroll
                for (int q = 0; q < 8; q++) {
                    acc.x = fmaf(ci[q], __int_as_float(vi[q] << 16), acc.x);
                    acc.y = fmaf(ci[q], __int_as_float(vi[q] & 0xffff0000u), acc.y);
                }
            }
            for (; j < deg; j++) {
                int s0 = __builtin_amdgcn_readlane(s, j);
                float c0 = rl_f(coef, j);
                unsigned v0 = hu[(size_t)s0 * 64 + lane];
                acc.x = fmaf(c0, __int_as_float(v0 << 16), acc.x);
                acc.y = fmaf(c0, __int_as_float(v0 & 0xffff0000u), acc.y);
            }
        } else {
            float m = -1e30f;
            for (int i = st + lane; i < en; i += 64) {
                float l = lrelu02(asn[csr[i]] + ad);
                m = fmaxf(m, l);
            }
#pragma unroll
            for (int o = 32; o; o >>= 1) m = fmaxf(m, __shfl_xor(m, o));
            float ssum = 0.f;
            for (int i = st + lane; i < en; i += 64) {
                float l = lrelu02(asn[csr[i]] + ad);
                ssum += __expf(l - m);
            }
#pragma unroll
            for (int o = 32; o; o >>= 1) ssum += __shfl_xor(ssum, o);
            float inv = 1.f / ssum;
            for (int base = st; base < en; base += 64) {
                int cnt = min(64, en - base);
                if (lane < cnt) {
                    int sx = csr[base + lane];
                    float l = lrelu02(asn[sx] + ad);
                    sh_e[w * 64 + lane] = __expf(l - m) * inv;
                    sh_s[w * 64 + lane] = sx;
                }
                for (int j = 0; j < cnt; j++) {
                    float c = sh_e[w * 64 + j];
                    int sx = sh_s[w * 64 + j];
                    unsigned v0 = hu[(size_t)sx * 64 + lane];
                    acc.x = fmaf(c, __int_as_float(v0 << 16), acc.x);
                    acc.y = fmaf(c, __int_as_float(v0 & 0xffff0000u), acc.y);
                }
            }
        }
        float2 b = ((const float2*)bias)[lane];
        float rx = gelu_f(acc.x + b.x);
        float ry = gelu_f(acc.y + b.y);
        if constexpr (OUT32) {
            ((float2*)outp)[(size_t)node * 64 + lane] = make_float2(rx, ry);
        } else {
            ((unsigned*)outp)[(size_t)node * 64 + lane] = pk2bf(rx, ry);
        }
    }
}

__device__ void phase_poolfc(const MegaArgs& A, char* smem) {
    float* gv = (float*)smem;           // 128 floats
    float* tmp = (float*)(smem + 512);  // 256 floats
    const int tid = threadIdx.x;
    for (int g = blockIdx.x; g < NUM_GRAPHS; g += gridDim.x) {
        int st, en;
        {
            int lo = 0, hi = N_NODES;
            while (lo < hi) { int mid = (lo + hi) >> 1; if (A.batch[mid] < g) lo = mid + 1; else hi = mid; }
            st = lo;
            lo = st; hi = N_NODES;
            while (lo < hi) { int mid = (lo + hi) >> 1; if (A.batch[mid] < g + 1) lo = mid + 1; else hi = mid; }
            en = lo;
        }
        int c = tid & 127;
        int half = tid >> 7;
        float acc = 0.f;
        for (int n = st + half; n < en; n += 2) acc += A.h3f[(size_t)n * HID + c];
        tmp[tid] = acc;
        __syncthreads();
        if (tid < HID) gv[tid] = tmp[tid] + tmp[tid + 128];
        __syncthreads();
        if (tid < OUT_DIM) {
            float a = A.fcb[tid];
#pragma unroll 4
            for (int k = 0; k < HID; k++) a = fmaf(gv[k], A.fcW[k * OUT_DIM + tid], a);
            A.out[g * OUT_DIM + tid] = a > 0.f ? a : 0.01f * a;
        }
        __syncthreads();
    }
}

// ================= cooperative mega-kernel ==============
__global__ __launch_bounds__(256, 4) void k_mega(MegaArgs A) {
    __shared__ __align__(16) char smem[4608];
    cg::grid_group grid = cg::this_grid();
    phase_p0(A);
    grid.sync();
    phase_bhist(A, (int*)smem);
    grid.sync();
    phase_bscan(A);
    grid.sync();
    phase_passA(A, (int*)smem, (int*)(smem + 1568));
    grid.sync();
    phase_passB(A, (int*)smem, (int*)(smem + 512), (int*)(smem + 1024));
    grid.sync();
    phase_mgemm<K1>((const unsigned short*)A.Abu, A.Wt1, A.a1s, A.a1d, A.hLin, A.asn, A.adn);
    grid.sync();
    phase_aggr<false>(A, A.hLin, A.b1, A.hAct, smem);
    grid.sync();
    phase_mgemm<HID>(A.hAct, A.Wt2, A.a2s, A.a2d, A.hLin, A.asn, A.adn);
    grid.sync();
    phase_aggr<false>(A, A.hLin, A.b2, A.hAct, smem);
    grid.sync();
    phase_mgemm<HID>(A.hAct, A.Wt3, A.a3s, A.a3d, A.hLin, A.asn, A.adn);
    grid.sync();
    phase_aggr<true>(A, A.hLin, A.b3, A.h3f, smem);
    grid.sync();
    phase_poolfc(A, smem);
}

// ================= fallback wrappers (round-5 proven path) ==============
__global__ __launch_bounds__(256) void kf_p0(MegaArgs A) { phase_p0(A); }
__global__ __launch_bounds__(256) void kf_bhist(MegaArgs A) {
    __shared__ int h[NB];
    phase_bhist(A, h);
}
__global__ __launch_bounds__(256) void kf_bscan(MegaArgs A) { phase_bscan(A); }
__global__ __launch_bounds__(256) void kf_passA(MegaArgs A) {
    __shared__ int h[NB];
    __shared__ int base[NB];
    phase_passA(A, h, base);
}
__global__ __launch_bounds__(256) void kf_passB(MegaArgs A) {
    __shared__ int dcnt[128], dsum[128], locOff[128];
    phase_passB(A, dcnt, dsum, locOff);
}
__global__ __launch_bounds__(256) void kf_mgemm1(MegaArgs A) {
    phase_mgemm<K1>((const unsigned short*)A.Abu, A.Wt1, A.a1s, A.a1d, A.hLin, A.asn, A.adn);
}
__global__ __launch_bounds__(256) void kf_mgemm2(MegaArgs A) {
    phase_mgemm<HID>(A.hAct, A.Wt2, A.a2s, A.a2d, A.hLin, A.asn, A.adn);
}
__global__ __launch_bounds__(256) void kf_mgemm3(MegaArgs A) {
    phase_mgemm<HID>(A.hAct, A.Wt3, A.a3s, A.a3d, A.hLin, A.asn, A.adn);
}
__global__ __launch_bounds__(256) void kf_aggr1(MegaArgs A) {
    __shared__ __align__(16) char smem[2048];
    phase_aggr<false>(A, A.hLin, A.b1, A.hAct, smem);
}
__global__ __launch_bounds__(256) void kf_aggr2(MegaArgs A) {
    __shared__ __align__(16) char smem[2048];
    phase_aggr<false>(A, A.hLin, A.b2, A.hAct, smem);
}
__global__ __launch_bounds__(256) void kf_aggr3(MegaArgs A) {
    __shared__ __align__(16) char smem[2048];
    phase_aggr<true>(A, A.hLin, A.b3, A.h3f, smem);
}
__global__ __launch_bounds__(256) void kf_poolfc(MegaArgs A) {
    __shared__ __align__(16) char smem[1536];
    phase_poolfc(A, smem);
}

extern "C" void kernel_launch(void* const* d_in, const int* in_sizes, int n_in,
                              void* d_out, int out_size, void* d_ws, size_t ws_size,
                              hipStream_t stream) {
    MegaArgs a;
    a.x    = (const float*)d_in[0];
    a.nidx = (const int*)d_in[1];
    const int* ei = (const int*)d_in[2];
    a.src  = ei;
    a.dst  = ei + N_EDGES;
    a.batch = (const int*)d_in[3];
    a.emb  = (const float*)d_in[4];
    a.W1 = (const float*)d_in[5];  a.a1s = (const float*)d_in[6];
    a.a1d = (const float*)d_in[7]; a.b1 = (const float*)d_in[8];
    a.W2 = (const float*)d_in[9];  a.a2s = (const float*)d_in[10];
    a.a2d = (const float*)d_in[11]; a.b2 = (const float*)d_in[12];
    a.W3 = (const float*)d_in[13]; a.a3s = (const float*)d_in[14];
    a.a3d = (const float*)d_in[15]; a.b3 = (const float*)d_in[16];
    a.fcW = (const float*)d_in[17]; a.fcb = (const float*)d_in[18];
    a.out = (float*)d_out;

    char* w = (char*)d_ws;
    auto alloc = [&](size_t bytes) -> char* {
        char* p = w;
        w += (bytes + 511) & ~(size_t)511;
        return p;
    };
    char* region0 = alloc((size_t)N_NODES * HID * 4);  // Abf bf16 [N,192] then h3f fp32 [N,128]
    a.Abu = (unsigned*)region0;
    a.h3f = (float*)region0;
    a.hLin = (unsigned short*)alloc((size_t)N_NODES * HID * 2);
    a.hAct = (unsigned short*)alloc((size_t)N_NODES * HID * 2);
    a.asn = (float*)alloc((size_t)N_NODES * 4);
    a.adn = (float*)alloc((size_t)N_NODES * 4);
    a.rowptr = (int*)alloc((size_t)(N_NODES + 1) * 4);
    a.bcnt = (int*)alloc((size_t)NB * 4);
    a.boff = (int*)alloc((size_t)(NB + 1) * 4);
    a.bfill = (int*)alloc((size_t)NB * 4);
    a.barr = (unsigned*)alloc((size_t)N_EDGES * 4);
    a.csr = (int*)alloc((size_t)E_TOT * 4);
    a.Wt1 = (unsigned short*)alloc((size_t)HID * K1 * 2);
    a.Wt2 = (unsigned short*)alloc((size_t)HID * HID * 2);
    a.Wt3 = (unsigned short*)alloc((size_t)HID * HID * 2);

    // occupancy-sized cooperative grid (pure queries — capture-safe)
    int dev = 0;
    hipError_t e0 = hipGetDevice(&dev);
    int numCU = 0;
    hipError_t e1 = hipDeviceGetAttribute(&numCU, hipDeviceAttributeMultiprocessorCount, dev);
    int maxB = 0;
    hipError_t qerr = hipOccupancyMaxActiveBlocksPerMultiprocessor(&maxB, k_mega, 256, 0);

    hipError_t lerr = hipErrorUnknown;
    if (e0 == hipSuccess && e1 == hipSuccess && qerr == hipSuccess && maxB >= 1 && numCU >= 1) {
        int grid = maxB * numCU;
        if (grid > 2048) grid = 2048;
        void* kp[] = { &a };
        lerr = hipLaunchCooperativeKernel(k_mega, dim3(grid), dim3(256), kp, 0, stream);
    }
    if (lerr != hipSuccess) {
        // deterministic fallback: round-5 proven multi-kernel sequence
        kf_p0<<<1024, 256, 0, stream>>>(a);
        kf_bhist<<<NCHUNK, 256, 0, stream>>>(a);
        kf_bscan<<<1, 256, 0, stream>>>(a);
        kf_passA<<<NCHUNK, 256, 0, stream>>>(a);
        kf_passB<<<NB, 256, 0, stream>>>(a);
        kf_mgemm1<<<NRG, 256, 0, stream>>>(a);
        kf_aggr1<<<NGRP, 256, 0, stream>>>(a);
        kf_mgemm2<<<NRG, 256, 0, stream>>>(a);
        kf_aggr2<<<NGRP, 256, 0, stream>>>(a);
        kf_mgemm3<<<NRG, 256, 0, stream>>>(a);
        kf_aggr3<<<NGRP, 256, 0, stream>>>(a);
        kf_poolfc<<<NUM_GRAPHS, 256, 0, stream>>>(a);
    }
}

// Round 9
// 402.050 us; speedup vs baseline: 1.0312x; 1.0312x over previous
//
#include <hip/hip_runtime.h>

#define N_NODES 50000
#define N_EDGES 800000
#define IN_DIM 128
#define EMB_DIM 64
#define HID 128
#define OUT_DIM 64
#define NUM_GRAPHS 128
#define E_TOT (N_EDGES + N_NODES)
#define K1 (IN_DIM + EMB_DIM)   // 192
#define NB 391                   // ceil(N_NODES/128) buckets of 128 dst nodes
#define EPB 4096
#define NCHUNK ((N_EDGES + EPB - 1) / EPB)  // 196
#define EPT 16                   // EPB / 256
#define NGRP 12500               // node groups of 4
#define NRG 782                  // row groups of 64 (mgemm)
#define P0B 588                  // p0 blocks inside k_hist_p0

typedef __attribute__((ext_vector_type(8))) short bf16x8;
typedef __attribute__((ext_vector_type(4))) float f32x4;

__device__ __forceinline__ float gelu_f(float x) {
    float x3 = x * x * x;
    return 0.5f * x * (1.0f + tanhf(0.7978845608028654f * (x + 0.044715f * x3)));
}
__device__ __forceinline__ float lrelu02(float x) { return x > 0.f ? x : 0.2f * x; }
__device__ __forceinline__ float rl_f(float v, int j) {
    return __int_as_float(__builtin_amdgcn_readlane(__float_as_int(v), j));
}
__device__ __forceinline__ unsigned short f2bf(float f) {  // RNE
    unsigned u = __float_as_uint(f);
    unsigned r = (u + 0x7fffu + ((u >> 16) & 1u)) >> 16;
    return (unsigned short)r;
}
__device__ __forceinline__ unsigned pk2bf(float a, float b) {
    return (unsigned)f2bf(a) | ((unsigned)f2bf(b) << 16);
}

struct Args {
    const float* x; const int* nidx; const int* src; const int* dst; const int* batch;
    const float* emb;
    const float* W1; const float* a1s; const float* a1d; const float* b1;
    const float* W2; const float* a2s; const float* a2d; const float* b2;
    const float* W3; const float* a3s; const float* a3d; const float* b3;
    const float* fcW; const float* fcb;
    float* out;
    unsigned* Abu; float* h3f;                       // aliased region
    unsigned short* hLin; unsigned short* hAct;
    float* asn; float* adn;
    int* rowptr; int* boff; int* chunkhist;          // chunkhist[NCHUNK][NB]
    unsigned* barr; int* csr;
    unsigned short* Wt1; unsigned short* Wt2; unsigned short* Wt3;
};

// ================= phase device functions ==============

// p0: W -> bf16 W^T (contig, stride K), A1 = [x/||x|| | emb] bf16
__device__ void phase_p0(const Args& A, int vbid, int vgrid) {
    const int tid = threadIdx.x;
    const int lane = tid & 63, wv = tid >> 6;
    const int gtid = vbid * 256 + tid;
    const int nthr = vgrid * 256;
    for (int id = gtid; id < 128 * K1; id += nthr) {
        int c = id / K1, k = id - c * K1;
        A.Wt1[c * K1 + k] = f2bf(A.W1[(size_t)k * HID + c]);
    }
    for (int id = gtid; id < 128 * 128; id += nthr) {
        int c = id >> 7, k = id & 127;
        A.Wt2[c * HID + k] = f2bf(A.W2[(size_t)k * HID + c]);
        A.Wt3[c * HID + k] = f2bf(A.W3[(size_t)k * HID + c]);
    }
    for (int g4 = vbid; g4 < NGRP; g4 += vgrid) {
        int node = g4 * 4 + wv;
        if (node >= N_NODES) continue;
        float2 v = ((const float2*)(A.x + (size_t)node * IN_DIM))[lane];
        float ss = v.x * v.x + v.y * v.y;
#pragma unroll
        for (int o = 32; o; o >>= 1) ss += __shfl_xor(ss, o);
        float nrm = sqrtf(ss);
        if (nrm == 0.f) nrm = 1e-8f;
        float inv = 1.f / nrm;
        unsigned* row = A.Abu + (size_t)node * (K1 / 2);
        row[lane] = pk2bf(v.x * inv, v.y * inv);
        int nid = __builtin_amdgcn_readfirstlane(A.nidx[node]);
        if (lane < 32) {
            float2 e = ((const float2*)(A.emb + (size_t)nid * EMB_DIM))[lane];
            row[64 + lane] = pk2bf(e.x, e.y);
        }
    }
}

template <int K>
__device__ void phase_mgemm(const Args& A, int rg, const unsigned short* __restrict__ Abf,
                            const unsigned short* __restrict__ Wt,
                            const float* __restrict__ a_s, const float* __restrict__ a_d,
                            unsigned short* __restrict__ Hbf) {
    const int lane = threadIdx.x & 63;
    const int wv = threadIdx.x >> 6;
    const int l15 = lane & 15, quad = lane >> 4;
    constexpr int NK = K / 32;
    int rowbase = rg * 64 + wv * 16;
    if (rowbase >= N_NODES) return;
    const unsigned short* Abase = Abf + (size_t)(rowbase + l15) * K + quad * 8;
    bf16x8 afr[NK];
#pragma unroll
    for (int i = 0; i < NK; i++) afr[i] = *(const bf16x8*)(Abase + i * 32);
    f32x4 acc[8];
#pragma unroll
    for (int t = 0; t < 8; t++) acc[t] = (f32x4){0.f, 0.f, 0.f, 0.f};
#pragma unroll
    for (int i = 0; i < NK; i++) {
#pragma unroll
        for (int t = 0; t < 8; t++) {
            bf16x8 bf = *(const bf16x8*)(Wt + (size_t)(t * 16 + l15) * K + i * 32 + quad * 8);
            acc[t] = __builtin_amdgcn_mfma_f32_16x16x32_bf16(afr[i], bf, acc[t], 0, 0, 0);
        }
    }
    float asc[8], adc[8];
#pragma unroll
    for (int t = 0; t < 8; t++) { asc[t] = a_s[t * 16 + l15]; adc[t] = a_d[t * 16 + l15]; }
#pragma unroll
    for (int r = 0; r < 4; r++) {
        int row = rowbase + quad * 4 + r;
        float ps = 0.f, pd = 0.f;
#pragma unroll
        for (int t = 0; t < 8; t++) {
            float v = acc[t][r];
            Hbf[(size_t)row * HID + t * 16 + l15] = f2bf(v);
            ps = fmaf(v, asc[t], ps);
            pd = fmaf(v, adc[t], pd);
        }
#pragma unroll
        for (int o = 1; o < 16; o <<= 1) {
            ps += __shfl_xor(ps, o);
            pd += __shfl_xor(pd, o);
        }
        if (l15 == 0) { A.asn[row] = ps; A.adn[row] = pd; }
    }
}

template <bool OUT32>
__device__ void phase_aggr(const Args& A, const unsigned short* __restrict__ hbf,
                           const float* __restrict__ bias, void* __restrict__ outp,
                           float* sh_e, int* sh_s) {
    const int lane = threadIdx.x & 63;
    const int w = threadIdx.x >> 6;
    const unsigned* hu = (const unsigned*)hbf;
    const int* rowptr = A.rowptr;
    const int* csr = A.csr;
    const float* asn = A.asn;
    const float* adn = A.adn;
    int node = blockIdx.x * 4 + w;
    if (node >= N_NODES) return;
    int st = rowptr[node], en = rowptr[node + 1];
    int deg = en - st;
    float ad = adn[node];
    float2 acc = make_float2(0.f, 0.f);
    if (deg <= 64) {
        int s = 0;
        float l = -1e30f;
        if (lane < deg) {
            s = csr[st + lane];
            l = lrelu02(asn[s] + ad);
        }
        float m = l;
#pragma unroll
        for (int o = 32; o; o >>= 1) m = fmaxf(m, __shfl_xor(m, o));
        float e = (lane < deg) ? __expf(l - m) : 0.f;
        float ssum = e;
#pragma unroll
        for (int o = 32; o; o >>= 1) ssum += __shfl_xor(ssum, o);
        float coef = e / ssum;
        int j = 0;
        for (; j + 8 <= deg; j += 8) {
            int si[8]; float ci[8]; unsigned vi[8];
#pragma unroll
            for (int q = 0; q < 8; q++) {
                si[q] = __builtin_amdgcn_readlane(s, j + q);
                ci[q] = rl_f(coef, j + q);
            }
#pragma unroll
            for (int q = 0; q < 8; q++) vi[q] = hu[(size_t)si[q] * 64 + lane];
#pragma unroll
            for (int q = 0; q < 8; q++) {
                acc.x = fmaf(ci[q], __int_as_float(vi[q] << 16), acc.x);
                acc.y = fmaf(ci[q], __int_as_float(vi[q] & 0xffff0000u), acc.y);
            }
        }
        for (; j < deg; j++) {
            int s0 = __builtin_amdgcn_readlane(s, j);
            float c0 = rl_f(coef, j);
            unsigned v0 = hu[(size_t)s0 * 64 + lane];
            acc.x = fmaf(c0, __int_as_float(v0 << 16), acc.x);
            acc.y = fmaf(c0, __int_as_float(v0 & 0xffff0000u), acc.y);
        }
    } else {
        float m = -1e30f;
        for (int i = st + lane; i < en; i += 64) {
            float l = lrelu02(asn[csr[i]] + ad);
            m = fmaxf(m, l);
        }
#pragma unroll
        for (int o = 32; o; o >>= 1) m = fmaxf(m, __shfl_xor(m, o));
        float ssum = 0.f;
        for (int i = st + lane; i < en; i += 64) {
            float l = lrelu02(asn[csr[i]] + ad);
            ssum += __expf(l - m);
        }
#pragma unroll
        for (int o = 32; o; o >>= 1) ssum += __shfl_xor(ssum, o);
        float inv = 1.f / ssum;
        for (int base = st; base < en; base += 64) {
            int cnt = min(64, en - base);
            if (lane < cnt) {
                int sx = csr[base + lane];
                float l = lrelu02(asn[sx] + ad);
                sh_e[w * 64 + lane] = __expf(l - m) * inv;
                sh_s[w * 64 + lane] = sx;
            }
            for (int j = 0; j < cnt; j++) {
                float c = sh_e[w * 64 + j];
                int sx = sh_s[w * 64 + j];
                unsigned v0 = hu[(size_t)sx * 64 + lane];
                acc.x = fmaf(c, __int_as_float(v0 << 16), acc.x);
                acc.y = fmaf(c, __int_as_float(v0 & 0xffff0000u), acc.y);
            }
        }
    }
    float2 b = ((const float2*)bias)[lane];
    float rx = gelu_f(acc.x + b.x);
    float ry = gelu_f(acc.y + b.y);
    if constexpr (OUT32) {
        ((float2*)outp)[(size_t)node * 64 + lane] = make_float2(rx, ry);
    } else {
        ((unsigned*)outp)[(size_t)node * 64 + lane] = pk2bf(rx, ry);
    }
}

// ================= kernels ==============

// bhist (blocks 0..NCHUNK-1, per-chunk histogram, no global atomics) || p0 (rest)
__global__ __launch_bounds__(256) void k_hist_p0(Args A) {
    if (blockIdx.x < NCHUNK) {
        __shared__ int h[NB];
        const int tid = threadIdx.x;
        const int c = blockIdx.x;
        for (int i = tid; i < NB; i += 256) h[i] = 0;
        __syncthreads();
        int e0 = c * EPB, e1 = min(e0 + EPB, N_EDGES);
        for (int e = e0 + tid; e < e1; e += 256) atomicAdd(&h[A.dst[e] >> 7], 1);
        __syncthreads();
        for (int i = tid; i < NB; i += 256) A.chunkhist[c * NB + i] = h[i];
    } else {
        phase_p0(A, blockIdx.x - NCHUNK, P0B);
    }
}

// block 0: chunkhist -> in-place exclusive prefix along chunks + bucket scan -> boff
// blocks 1..NRG: mgemm layer 1
__global__ __launch_bounds__(256) void k_scan_mgemm1(Args A) {
    if (blockIdx.x == 0) {
        __shared__ int tot[NB];
        const int tid = threadIdx.x;
        for (int b = tid; b < NB; b += 256) {
            int run = 0;
            for (int c = 0; c < NCHUNK; c++) {
                int idx = c * NB + b;
                int v = A.chunkhist[idx];
                A.chunkhist[idx] = run;
                run += v;
            }
            tot[b] = run;
        }
        __syncthreads();
        if (tid < 64) {
            int lane = tid;
            int run = 0;
            for (int c7 = 0; c7 < 7; c7++) {
                int i = c7 * 64 + lane;
                int v = (i < NB) ? tot[i] : 0;
                int s = v;
#pragma unroll
                for (int o = 1; o < 64; o <<= 1) {
                    int u = __shfl_up(s, o);
                    if (lane >= o) s += u;
                }
                if (i < NB) A.boff[i] = run + s - v;
                run += __shfl(s, 63);
            }
            if (lane == 0) { A.boff[NB] = N_EDGES; A.rowptr[N_NODES] = E_TOT; }
        }
    } else {
        phase_mgemm<K1>(A, blockIdx.x - 1, (const unsigned short*)A.Abu, A.Wt1, A.a1s, A.a1d, A.hLin);
    }
}

// passA: partition edges bucket-major; offsets from boff + chunkoff (no global atomics)
__global__ __launch_bounds__(256) void k_passA(Args A) {
    __shared__ int h[NB];
    __shared__ int base[NB];
    const int tid = threadIdx.x;
    const int c = blockIdx.x;
    for (int i = tid; i < NB; i += 256) {
        h[i] = 0;
        base[i] = A.boff[i] + A.chunkhist[c * NB + i];
    }
    __syncthreads();
    int e0 = c * EPB;
    int tag[EPT];
#pragma unroll
    for (int i = 0; i < EPT; i++) {
        int e = e0 + i * 256 + tid;
        tag[i] = -1;
        if (e < N_EDGES) {
            int b = A.dst[e] >> 7;
            int r = atomicAdd(&h[b], 1);  // LDS rank, r < 4096
            tag[i] = (b << 12) | r;
        }
    }
#pragma unroll
    for (int i = 0; i < EPT; i++) {
        if (tag[i] >= 0) {
            int e = e0 + i * 256 + tid;
            int b = tag[i] >> 12, r = tag[i] & 0xfff;
            A.barr[base[b] + r] = (unsigned)A.src[e] | ((unsigned)(A.dst[e] & 127) << 16);
        }
    }
}

// passB: per-bucket CSR build (self loop at slot 0)
__global__ __launch_bounds__(256) void k_passB(Args A) {
    __shared__ int dcnt[128], dsum[128], locOff[128];
    const int tid = threadIdx.x;
    const int b = blockIdx.x;
    int n0 = b << 7;
    int cnt = min(128, N_NODES - n0);
    int eb = A.boff[b], ee = A.boff[b + 1];
    if (tid < 128) dcnt[tid] = 0;
    __syncthreads();
    for (int i = eb + tid; i < ee; i += 256) atomicAdd(&dcnt[A.barr[i] >> 16], 1);
    __syncthreads();
    int v = 0;
    if (tid < 128) {
        v = (tid < cnt) ? dcnt[tid] + 1 : 0;
        dsum[tid] = v;
    }
    __syncthreads();
    for (int o = 1; o < 128; o <<= 1) {
        int u = (tid >= o && tid < 128) ? dsum[tid - o] : 0;
        __syncthreads();
        if (tid < 128) dsum[tid] += u;
        __syncthreads();
    }
    int csrBase = eb + n0;
    if (tid < 128) {
        locOff[tid] = dsum[tid] - v;
        dcnt[tid] = 0;
    }
    if (tid < cnt) {
        int loc = dsum[tid] - v;
        A.rowptr[n0 + tid] = csrBase + loc;
        A.csr[csrBase + loc] = n0 + tid;  // self loop at slot 0
    }
    __syncthreads();
    for (int i = eb + tid; i < ee; i += 256) {
        unsigned vv = A.barr[i];
        int dl = vv >> 16;
        int s = (int)(vv & 0xffffu);
        int k = atomicAdd(&dcnt[dl], 1);
        A.csr[csrBase + locOff[dl] + 1 + k] = s;
    }
}

__global__ __launch_bounds__(256) void k_mgemm2(Args A) {
    phase_mgemm<HID>(A, blockIdx.x, A.hAct, A.Wt2, A.a2s, A.a2d, A.hLin);
}
__global__ __launch_bounds__(256) void k_mgemm3(Args A) {
    phase_mgemm<HID>(A, blockIdx.x, A.hAct, A.Wt3, A.a3s, A.a3d, A.hLin);
}
__global__ __launch_bounds__(256) void k_aggr1(Args A) {
    __shared__ float sh_e[256];
    __shared__ int sh_s[256];
    phase_aggr<false>(A, A.hLin, A.b1, A.hAct, sh_e, sh_s);
}
__global__ __launch_bounds__(256) void k_aggr2(Args A) {
    __shared__ float sh_e[256];
    __shared__ int sh_s[256];
    phase_aggr<false>(A, A.hLin, A.b2, A.hAct, sh_e, sh_s);
}
__global__ __launch_bounds__(256) void k_aggr3(Args A) {
    __shared__ float sh_e[256];
    __shared__ int sh_s[256];
    phase_aggr<true>(A, A.hLin, A.b3, A.h3f, sh_e, sh_s);
}

__global__ __launch_bounds__(256) void k_poolfc(Args A) {
    __shared__ float gv[HID];
    __shared__ float tmp[256];
    const int tid = threadIdx.x;
    const int g = blockIdx.x;
    int st, en;
    {
        int lo = 0, hi = N_NODES;
        while (lo < hi) { int mid = (lo + hi) >> 1; if (A.batch[mid] < g) lo = mid + 1; else hi = mid; }
        st = lo;
        lo = st; hi = N_NODES;
        while (lo < hi) { int mid = (lo + hi) >> 1; if (A.batch[mid] < g + 1) lo = mid + 1; else hi = mid; }
        en = lo;
    }
    int c = tid & 127;
    int half = tid >> 7;
    float acc = 0.f;
    for (int n = st + half; n < en; n += 2) acc += A.h3f[(size_t)n * HID + c];
    tmp[tid] = acc;
    __syncthreads();
    if (tid < HID) gv[tid] = tmp[tid] + tmp[tid + 128];
    __syncthreads();
    if (tid < OUT_DIM) {
        float a = A.fcb[tid];
#pragma unroll 4
        for (int k = 0; k < HID; k++) a = fmaf(gv[k], A.fcW[k * OUT_DIM + tid], a);
        A.out[g * OUT_DIM + tid] = a > 0.f ? a : 0.01f * a;
    }
}

extern "C" void kernel_launch(void* const* d_in, const int* in_sizes, int n_in,
                              void* d_out, int out_size, void* d_ws, size_t ws_size,
                              hipStream_t stream) {
    Args a;
    a.x    = (const float*)d_in[0];
    a.nidx = (const int*)d_in[1];
    const int* ei = (const int*)d_in[2];
    a.src  = ei;
    a.dst  = ei + N_EDGES;
    a.batch = (const int*)d_in[3];
    a.emb  = (const float*)d_in[4];
    a.W1 = (const float*)d_in[5];  a.a1s = (const float*)d_in[6];
    a.a1d = (const float*)d_in[7]; a.b1 = (const float*)d_in[8];
    a.W2 = (const float*)d_in[9];  a.a2s = (const float*)d_in[10];
    a.a2d = (const float*)d_in[11]; a.b2 = (const float*)d_in[12];
    a.W3 = (const float*)d_in[13]; a.a3s = (const float*)d_in[14];
    a.a3d = (const float*)d_in[15]; a.b3 = (const float*)d_in[16];
    a.fcW = (const float*)d_in[17]; a.fcb = (const float*)d_in[18];
    a.out = (float*)d_out;

    char* w = (char*)d_ws;
    auto alloc = [&](size_t bytes) -> char* {
        char* p = w;
        w += (bytes + 511) & ~(size_t)511;
        return p;
    };
    char* region0 = alloc((size_t)N_NODES * HID * 4);  // Abf bf16 [N,192] then h3f fp32 [N,128]
    a.Abu = (unsigned*)region0;
    a.h3f = (float*)region0;
    a.hLin = (unsigned short*)alloc((size_t)N_NODES * HID * 2);
    a.hAct = (unsigned short*)alloc((size_t)N_NODES * HID * 2);
    a.asn = (float*)alloc((size_t)N_NODES * 4);
    a.adn = (float*)alloc((size_t)N_NODES * 4);
    a.rowptr = (int*)alloc((size_t)(N_NODES + 1) * 4);
    a.boff = (int*)alloc((size_t)(NB + 1) * 4);
    a.chunkhist = (int*)alloc((size_t)NCHUNK * NB * 4);   // 306 KB
    a.barr = (unsigned*)alloc((size_t)N_EDGES * 4);
    a.csr = (int*)alloc((size_t)E_TOT * 4);
    a.Wt1 = (unsigned short*)alloc((size_t)HID * K1 * 2);
    a.Wt2 = (unsigned short*)alloc((size_t)HID * HID * 2);
    a.Wt3 = (unsigned short*)alloc((size_t)HID * HID * 2);

    k_hist_p0<<<NCHUNK + P0B, 256, 0, stream>>>(a);      // bhist || p0
    k_scan_mgemm1<<<1 + NRG, 256, 0, stream>>>(a);       // scan || mgemm1
    k_passA<<<NCHUNK, 256, 0, stream>>>(a);
    k_passB<<<NB, 256, 0, stream>>>(a);
    k_aggr1<<<NGRP, 256, 0, stream>>>(a);
    k_mgemm2<<<NRG, 256, 0, stream>>>(a);
    k_aggr2<<<NGRP, 256, 0, stream>>>(a);
    k_mgemm3<<<NRG, 256, 0, stream>>>(a);
    k_aggr3<<<NGRP, 256, 0, stream>>>(a);
    k_poolfc<<<NUM_GRAPHS, 256, 0, stream>>>(a);
}

// Round 10
// 376.590 us; speedup vs baseline: 1.1010x; 1.0676x over previous
//
#include <hip/hip_runtime.h>

#define N_NODES 50000
#define N_EDGES 800000
#define IN_DIM 128
#define EMB_DIM 64
#define HID 128
#define OUT_DIM 64
#define NUM_GRAPHS 128
#define E_TOT (N_EDGES + N_NODES)
#define K1 (IN_DIM + EMB_DIM)   // 192
#define NB 391                   // ceil(N_NODES/128) buckets of 128 dst nodes
#define EPB 4096
#define NCHUNK ((N_EDGES + EPB - 1) / EPB)  // 196 (49 int4s per bucket row)
#define EPT 16                   // EPB / 256
#define NGRP 12500               // node groups of 4
#define NRG 782                  // row groups of 64 (mgemm)
#define P0B 588                  // p0 blocks inside k_hist_p0

typedef __attribute__((ext_vector_type(8))) short bf16x8;
typedef __attribute__((ext_vector_type(4))) float f32x4;

__device__ __forceinline__ float gelu_f(float x) {
    float x3 = x * x * x;
    return 0.5f * x * (1.0f + tanhf(0.7978845608028654f * (x + 0.044715f * x3)));
}
__device__ __forceinline__ float lrelu02(float x) { return x > 0.f ? x : 0.2f * x; }
__device__ __forceinline__ float rl_f(float v, int j) {
    return __int_as_float(__builtin_amdgcn_readlane(__float_as_int(v), j));
}
__device__ __forceinline__ unsigned short f2bf(float f) {  // RNE
    unsigned u = __float_as_uint(f);
    unsigned r = (u + 0x7fffu + ((u >> 16) & 1u)) >> 16;
    return (unsigned short)r;
}
__device__ __forceinline__ unsigned pk2bf(float a, float b) {
    return (unsigned)f2bf(a) | ((unsigned)f2bf(b) << 16);
}

struct Args {
    const float* x; const int* nidx; const int* src; const int* dst; const int* batch;
    const float* emb;
    const float* W1; const float* a1s; const float* a1d; const float* b1;
    const float* W2; const float* a2s; const float* a2d; const float* b2;
    const float* W3; const float* a3s; const float* a3d; const float* b3;
    const float* fcW; const float* fcb;
    float* out;
    unsigned* Abu; float* h3f;                       // aliased region
    unsigned short* hLin; unsigned short* hAct;
    float* asn; float* adn;
    int* rowptr; int* boff; int* chunkhist;          // chunkhist[NB][NCHUNK] (bucket-major)
    unsigned* barr; int* csr;
    unsigned short* Wt1; unsigned short* Wt2; unsigned short* Wt3;
};

// ================= phase device functions ==============

// p0: W -> bf16 W^T (contig, stride K), A1 = [x/||x|| | emb] bf16
__device__ void phase_p0(const Args& A, int vbid, int vgrid) {
    const int tid = threadIdx.x;
    const int lane = tid & 63, wv = tid >> 6;
    const int gtid = vbid * 256 + tid;
    const int nthr = vgrid * 256;
    for (int id = gtid; id < 128 * K1; id += nthr) {
        int c = id / K1, k = id - c * K1;
        A.Wt1[c * K1 + k] = f2bf(A.W1[(size_t)k * HID + c]);
    }
    for (int id = gtid; id < 128 * 128; id += nthr) {
        int c = id >> 7, k = id & 127;
        A.Wt2[c * HID + k] = f2bf(A.W2[(size_t)k * HID + c]);
        A.Wt3[c * HID + k] = f2bf(A.W3[(size_t)k * HID + c]);
    }
    for (int g4 = vbid; g4 < NGRP; g4 += vgrid) {
        int node = g4 * 4 + wv;
        if (node >= N_NODES) continue;
        float2 v = ((const float2*)(A.x + (size_t)node * IN_DIM))[lane];
        float ss = v.x * v.x + v.y * v.y;
#pragma unroll
        for (int o = 32; o; o >>= 1) ss += __shfl_xor(ss, o);
        float nrm = sqrtf(ss);
        if (nrm == 0.f) nrm = 1e-8f;
        float inv = 1.f / nrm;
        unsigned* row = A.Abu + (size_t)node * (K1 / 2);
        row[lane] = pk2bf(v.x * inv, v.y * inv);
        int nid = __builtin_amdgcn_readfirstlane(A.nidx[node]);
        if (lane < 32) {
            float2 e = ((const float2*)(A.emb + (size_t)nid * EMB_DIM))[lane];
            row[64 + lane] = pk2bf(e.x, e.y);
        }
    }
}

template <int K>
__device__ void phase_mgemm(const Args& A, int rg, const unsigned short* __restrict__ Abf,
                            const unsigned short* __restrict__ Wt,
                            const float* __restrict__ a_s, const float* __restrict__ a_d,
                            unsigned short* __restrict__ Hbf) {
    const int lane = threadIdx.x & 63;
    const int wv = threadIdx.x >> 6;
    const int l15 = lane & 15, quad = lane >> 4;
    constexpr int NK = K / 32;
    int rowbase = rg * 64 + wv * 16;
    if (rowbase >= N_NODES) return;
    const unsigned short* Abase = Abf + (size_t)(rowbase + l15) * K + quad * 8;
    bf16x8 afr[NK];
#pragma unroll
    for (int i = 0; i < NK; i++) afr[i] = *(const bf16x8*)(Abase + i * 32);
    f32x4 acc[8];
#pragma unroll
    for (int t = 0; t < 8; t++) acc[t] = (f32x4){0.f, 0.f, 0.f, 0.f};
#pragma unroll
    for (int i = 0; i < NK; i++) {
#pragma unroll
        for (int t = 0; t < 8; t++) {
            bf16x8 bf = *(const bf16x8*)(Wt + (size_t)(t * 16 + l15) * K + i * 32 + quad * 8);
            acc[t] = __builtin_amdgcn_mfma_f32_16x16x32_bf16(afr[i], bf, acc[t], 0, 0, 0);
        }
    }
    float asc[8], adc[8];
#pragma unroll
    for (int t = 0; t < 8; t++) { asc[t] = a_s[t * 16 + l15]; adc[t] = a_d[t * 16 + l15]; }
#pragma unroll
    for (int r = 0; r < 4; r++) {
        int row = rowbase + quad * 4 + r;
        float ps = 0.f, pd = 0.f;
#pragma unroll
        for (int t = 0; t < 8; t++) {
            float v = acc[t][r];
            Hbf[(size_t)row * HID + t * 16 + l15] = f2bf(v);
            ps = fmaf(v, asc[t], ps);
            pd = fmaf(v, adc[t], pd);
        }
#pragma unroll
        for (int o = 1; o < 16; o <<= 1) {
            ps += __shfl_xor(ps, o);
            pd += __shfl_xor(pd, o);
        }
        if (l15 == 0) { A.asn[row] = ps; A.adn[row] = pd; }
    }
}

template <bool OUT32>
__device__ void phase_aggr(const Args& A, const unsigned short* __restrict__ hbf,
                           const float* __restrict__ bias, void* __restrict__ outp,
                           float* sh_e, int* sh_s) {
    const int lane = threadIdx.x & 63;
    const int w = threadIdx.x >> 6;
    const unsigned* hu = (const unsigned*)hbf;
    const int* rowptr = A.rowptr;
    const int* csr = A.csr;
    const float* asn = A.asn;
    const float* adn = A.adn;
    int node = blockIdx.x * 4 + w;
    if (node >= N_NODES) return;
    int st = rowptr[node], en = rowptr[node + 1];
    int deg = en - st;
    float ad = adn[node];
    float2 acc = make_float2(0.f, 0.f);
    if (deg <= 64) {
        int s = 0;
        float l = -1e30f;
        if (lane < deg) {
            s = csr[st + lane];
            l = lrelu02(asn[s] + ad);
        }
        float m = l;
#pragma unroll
        for (int o = 32; o; o >>= 1) m = fmaxf(m, __shfl_xor(m, o));
        float e = (lane < deg) ? __expf(l - m) : 0.f;
        float ssum = e;
#pragma unroll
        for (int o = 32; o; o >>= 1) ssum += __shfl_xor(ssum, o);
        float coef = e / ssum;
        int j = 0;
        for (; j + 8 <= deg; j += 8) {
            int si[8]; float ci[8]; unsigned vi[8];
#pragma unroll
            for (int q = 0; q < 8; q++) {
                si[q] = __builtin_amdgcn_readlane(s, j + q);
                ci[q] = rl_f(coef, j + q);
            }
#pragma unroll
            for (int q = 0; q < 8; q++) vi[q] = hu[(size_t)si[q] * 64 + lane];
#pragma unroll
            for (int q = 0; q < 8; q++) {
                acc.x = fmaf(ci[q], __int_as_float(vi[q] << 16), acc.x);
                acc.y = fmaf(ci[q], __int_as_float(vi[q] & 0xffff0000u), acc.y);
            }
        }
        for (; j < deg; j++) {
            int s0 = __builtin_amdgcn_readlane(s, j);
            float c0 = rl_f(coef, j);
            unsigned v0 = hu[(size_t)s0 * 64 + lane];
            acc.x = fmaf(c0, __int_as_float(v0 << 16), acc.x);
            acc.y = fmaf(c0, __int_as_float(v0 & 0xffff0000u), acc.y);
        }
    } else {
        float m = -1e30f;
        for (int i = st + lane; i < en; i += 64) {
            float l = lrelu02(asn[csr[i]] + ad);
            m = fmaxf(m, l);
        }
#pragma unroll
        for (int o = 32; o; o >>= 1) m = fmaxf(m, __shfl_xor(m, o));
        float ssum = 0.f;
        for (int i = st + lane; i < en; i += 64) {
            float l = lrelu02(asn[csr[i]] + ad);
            ssum += __expf(l - m);
        }
#pragma unroll
        for (int o = 32; o; o >>= 1) ssum += __shfl_xor(ssum, o);
        float inv = 1.f / ssum;
        for (int base = st; base < en; base += 64) {
            int cnt = min(64, en - base);
            if (lane < cnt) {
                int sx = csr[base + lane];
                float l = lrelu02(asn[sx] + ad);
                sh_e[w * 64 + lane] = __expf(l - m) * inv;
                sh_s[w * 64 + lane] = sx;
            }
            for (int j = 0; j < cnt; j++) {
                float c = sh_e[w * 64 + j];
                int sx = sh_s[w * 64 + j];
                unsigned v0 = hu[(size_t)sx * 64 + lane];
                acc.x = fmaf(c, __int_as_float(v0 << 16), acc.x);
                acc.y = fmaf(c, __int_as_float(v0 & 0xffff0000u), acc.y);
            }
        }
    }
    float2 b = ((const float2*)bias)[lane];
    float rx = gelu_f(acc.x + b.x);
    float ry = gelu_f(acc.y + b.y);
    if constexpr (OUT32) {
        ((float2*)outp)[(size_t)node * 64 + lane] = make_float2(rx, ry);
    } else {
        ((unsigned*)outp)[(size_t)node * 64 + lane] = pk2bf(rx, ry);
    }
}

// ================= kernels ==============

// bhist (blocks 0..NCHUNK-1, per-chunk histogram, transposed write) || p0 (rest)
__global__ __launch_bounds__(256) void k_hist_p0(Args A) {
    if (blockIdx.x < NCHUNK) {
        __shared__ int h[NB];
        const int tid = threadIdx.x;
        const int c = blockIdx.x;
        for (int i = tid; i < NB; i += 256) h[i] = 0;
        __syncthreads();
        int e0 = c * EPB, e1 = min(e0 + EPB, N_EDGES);
        for (int e = e0 + tid; e < e1; e += 256) atomicAdd(&h[A.dst[e] >> 7], 1);
        __syncthreads();
        for (int i = tid; i < NB; i += 256) A.chunkhist[i * NCHUNK + c] = h[i];
    } else {
        phase_p0(A, blockIdx.x - NCHUNK, P0B);
    }
}

// block 0: per-bucket contiguous int4 prefix over chunks (parallel across buckets) + bucket scan
// blocks 1..NRG: mgemm layer 1
__global__ __launch_bounds__(256) void k_scan_mgemm1(Args A) {
    if (blockIdx.x == 0) {
        __shared__ int tot[NB];
        const int tid = threadIdx.x;
        for (int b = tid; b < NB; b += 256) {
            int4* p = (int4*)(A.chunkhist + (size_t)b * NCHUNK);  // 196 ints = 49 int4, 16B-aligned
            int run = 0;
#pragma unroll 7
            for (int q = 0; q < NCHUNK / 4; q++) {
                int4 v = p[q];
                int4 o;
                o.x = run;
                o.y = run + v.x;
                o.z = run + v.x + v.y;
                o.w = run + v.x + v.y + v.z;
                run += v.x + v.y + v.z + v.w;
                p[q] = o;
            }
            tot[b] = run;
        }
        __syncthreads();
        if (tid < 64) {
            int lane = tid;
            int run = 0;
            for (int c7 = 0; c7 < 7; c7++) {
                int i = c7 * 64 + lane;
                int v = (i < NB) ? tot[i] : 0;
                int s = v;
#pragma unroll
                for (int o = 1; o < 64; o <<= 1) {
                    int u = __shfl_up(s, o);
                    if (lane >= o) s += u;
                }
                if (i < NB) A.boff[i] = run + s - v;
                run += __shfl(s, 63);
            }
            if (lane == 0) { A.boff[NB] = N_EDGES; A.rowptr[N_NODES] = E_TOT; }
        }
    } else {
        phase_mgemm<K1>(A, blockIdx.x - 1, (const unsigned short*)A.Abu, A.Wt1, A.a1s, A.a1d, A.hLin);
    }
}

// passA: partition edges bucket-major; offsets from boff + per-(bucket,chunk) prefix (no global atomics)
__global__ __launch_bounds__(256) void k_passA(Args A) {
    __shared__ int h[NB];
    __shared__ int base[NB];
    const int tid = threadIdx.x;
    const int c = blockIdx.x;
    for (int i = tid; i < NB; i += 256) {
        h[i] = 0;
        base[i] = A.boff[i] + A.chunkhist[i * NCHUNK + c];
    }
    __syncthreads();
    int e0 = c * EPB;
    int tag[EPT];
#pragma unroll
    for (int i = 0; i < EPT; i++) {
        int e = e0 + i * 256 + tid;
        tag[i] = -1;
        if (e < N_EDGES) {
            int b = A.dst[e] >> 7;
            int r = atomicAdd(&h[b], 1);  // LDS rank, r < 4096
            tag[i] = (b << 12) | r;
        }
    }
#pragma unroll
    for (int i = 0; i < EPT; i++) {
        if (tag[i] >= 0) {
            int e = e0 + i * 256 + tid;
            int b = tag[i] >> 12, r = tag[i] & 0xfff;
            A.barr[base[b] + r] = (unsigned)A.src[e] | ((unsigned)(A.dst[e] & 127) << 16);
        }
    }
}

// passB: per-bucket CSR build (self loop at slot 0)
__global__ __launch_bounds__(256) void k_passB(Args A) {
    __shared__ int dcnt[128], dsum[128], locOff[128];
    const int tid = threadIdx.x;
    const int b = blockIdx.x;
    int n0 = b << 7;
    int cnt = min(128, N_NODES - n0);
    int eb = A.boff[b], ee = A.boff[b + 1];
    if (tid < 128) dcnt[tid] = 0;
    __syncthreads();
    for (int i = eb + tid; i < ee; i += 256) atomicAdd(&dcnt[A.barr[i] >> 16], 1);
    __syncthreads();
    int v = 0;
    if (tid < 128) {
        v = (tid < cnt) ? dcnt[tid] + 1 : 0;
        dsum[tid] = v;
    }
    __syncthreads();
    for (int o = 1; o < 128; o <<= 1) {
        int u = (tid >= o && tid < 128) ? dsum[tid - o] : 0;
        __syncthreads();
        if (tid < 128) dsum[tid] += u;
        __syncthreads();
    }
    int csrBase = eb + n0;
    if (tid < 128) {
        locOff[tid] = dsum[tid] - v;
        dcnt[tid] = 0;
    }
    if (tid < cnt) {
        int loc = dsum[tid] - v;
        A.rowptr[n0 + tid] = csrBase + loc;
        A.csr[csrBase + loc] = n0 + tid;  // self loop at slot 0
    }
    __syncthreads();
    for (int i = eb + tid; i < ee; i += 256) {
        unsigned vv = A.barr[i];
        int dl = vv >> 16;
        int s = (int)(vv & 0xffffu);
        int k = atomicAdd(&dcnt[dl], 1);
        A.csr[csrBase + locOff[dl] + 1 + k] = s;
    }
}

__global__ __launch_bounds__(256) void k_mgemm2(Args A) {
    phase_mgemm<HID>(A, blockIdx.x, A.hAct, A.Wt2, A.a2s, A.a2d, A.hLin);
}
__global__ __launch_bounds__(256) void k_mgemm3(Args A) {
    phase_mgemm<HID>(A, blockIdx.x, A.hAct, A.Wt3, A.a3s, A.a3d, A.hLin);
}
__global__ __launch_bounds__(256) void k_aggr1(Args A) {
    __shared__ float sh_e[256];
    __shared__ int sh_s[256];
    phase_aggr<false>(A, A.hLin, A.b1, A.hAct, sh_e, sh_s);
}
__global__ __launch_bounds__(256) void k_aggr2(Args A) {
    __shared__ float sh_e[256];
    __shared__ int sh_s[256];
    phase_aggr<false>(A, A.hLin, A.b2, A.hAct, sh_e, sh_s);
}
__global__ __launch_bounds__(256) void k_aggr3(Args A) {
    __shared__ float sh_e[256];
    __shared__ int sh_s[256];
    phase_aggr<true>(A, A.hLin, A.b3, A.h3f, sh_e, sh_s);
}

// pool+fc: 1024 threads, 8 row-streams per channel (ILP), then in-block fc
__global__ __launch_bounds__(1024) void k_poolfc(Args A) {
    __shared__ float tmp[1024];
    __shared__ float gv[HID];
    const int tid = threadIdx.x;
    const int g = blockIdx.x;
    int st, en;
    {
        int lo = 0, hi = N_NODES;
        while (lo < hi) { int mid = (lo + hi) >> 1; if (A.batch[mid] < g) lo = mid + 1; else hi = mid; }
        st = lo;
        lo = st; hi = N_NODES;
        while (lo < hi) { int mid = (lo + hi) >> 1; if (A.batch[mid] < g + 1) lo = mid + 1; else hi = mid; }
        en = lo;
    }
    int c = tid & 127;
    int r = tid >> 7;  // 0..7 row streams
    float acc = 0.f;
#pragma unroll 4
    for (int n = st + r; n < en; n += 8) acc += A.h3f[(size_t)n * HID + c];
    tmp[tid] = acc;
    __syncthreads();
    if (tid < HID) {
        float s = 0.f;
#pragma unroll
        for (int q = 0; q < 8; q++) s += tmp[q * 128 + tid];
        gv[tid] = s;
    }
    __syncthreads();
    if (tid < OUT_DIM) {
        float a = A.fcb[tid];
#pragma unroll 4
        for (int k = 0; k < HID; k++) a = fmaf(gv[k], A.fcW[k * OUT_DIM + tid], a);
        A.out[g * OUT_DIM + tid] = a > 0.f ? a : 0.01f * a;
    }
}

extern "C" void kernel_launch(void* const* d_in, const int* in_sizes, int n_in,
                              void* d_out, int out_size, void* d_ws, size_t ws_size,
                              hipStream_t stream) {
    Args a;
    a.x    = (const float*)d_in[0];
    a.nidx = (const int*)d_in[1];
    const int* ei = (const int*)d_in[2];
    a.src  = ei;
    a.dst  = ei + N_EDGES;
    a.batch = (const int*)d_in[3];
    a.emb  = (const float*)d_in[4];
    a.W1 = (const float*)d_in[5];  a.a1s = (const float*)d_in[6];
    a.a1d = (const float*)d_in[7]; a.b1 = (const float*)d_in[8];
    a.W2 = (const float*)d_in[9];  a.a2s = (const float*)d_in[10];
    a.a2d = (const float*)d_in[11]; a.b2 = (const float*)d_in[12];
    a.W3 = (const float*)d_in[13]; a.a3s = (const float*)d_in[14];
    a.a3d = (const float*)d_in[15]; a.b3 = (const float*)d_in[16];
    a.fcW = (const float*)d_in[17]; a.fcb = (const float*)d_in[18];
    a.out = (float*)d_out;

    char* w = (char*)d_ws;
    auto alloc = [&](size_t bytes) -> char* {
        char* p = w;
        w += (bytes + 511) & ~(size_t)511;
        return p;
    };
    char* region0 = alloc((size_t)N_NODES * HID * 4);  // Abf bf16 [N,192] then h3f fp32 [N,128]
    a.Abu = (unsigned*)region0;
    a.h3f = (float*)region0;
    a.hLin = (unsigned short*)alloc((size_t)N_NODES * HID * 2);
    a.hAct = (unsigned short*)alloc((size_t)N_NODES * HID * 2);
    a.asn = (float*)alloc((size_t)N_NODES * 4);
    a.adn = (float*)alloc((size_t)N_NODES * 4);
    a.rowptr = (int*)alloc((size_t)(N_NODES + 1) * 4);
    a.boff = (int*)alloc((size_t)(NB + 1) * 4);
    a.chunkhist = (int*)alloc((size_t)NB * NCHUNK * 4);   // 306 KB, bucket-major
    a.barr = (unsigned*)alloc((size_t)N_EDGES * 4);
    a.csr = (int*)alloc((size_t)E_TOT * 4);
    a.Wt1 = (unsigned short*)alloc((size_t)HID * K1 * 2);
    a.Wt2 = (unsigned short*)alloc((size_t)HID * HID * 2);
    a.Wt3 = (unsigned short*)alloc((size_t)HID * HID * 2);

    k_hist_p0<<<NCHUNK + P0B, 256, 0, stream>>>(a);      // bhist || p0
    k_scan_mgemm1<<<1 + NRG, 256, 0, stream>>>(a);       // parallel scan || mgemm1
    k_passA<<<NCHUNK, 256, 0, stream>>>(a);
    k_passB<<<NB, 256, 0, stream>>>(a);
    k_aggr1<<<NGRP, 256, 0, stream>>>(a);
    k_mgemm2<<<NRG, 256, 0, stream>>>(a);
    k_aggr2<<<NGRP, 256, 0, stream>>>(a);
    k_mgemm3<<<NRG, 256, 0, stream>>>(a);
    k_aggr3<<<NGRP, 256, 0, stream>>>(a);
    k_poolfc<<<NUM_GRAPHS, 1024, 0, stream>>>(a);
}